// Round 1
// baseline (260.792 us; speedup 1.0000x reference)
//
#include <hip/hip_runtime.h>

// DistanceNorm: (B, L, M) f32.
//  Pass A: partial column sums over L-chunks        -> ws partial [B][LCH][M] f32
//  Pass B: reduce partials, compute scale[b], idx   -> ws new_idx [B][M] i32
//  Pass C: out[b,l,m] = d[b,l,new_idx[b,m]]
// Memory-bound: ~384 MiB total traffic, target ~60-70 us.

constexpr int L = 2048;
constexpr int M = 1024;
constexpr int LCH = 64;            // L-chunks in pass A
constexpr int ROWS = L / LCH;      // 32 rows per block

__global__ __launch_bounds__(256) void colsum_partial(
    const float* __restrict__ d, float* __restrict__ partial) {
    const int blk = blockIdx.x;            // b * LCH + lch
    const int b   = blk / LCH;
    const int lch = blk % LCH;
    const int t   = threadIdx.x;           // 0..255; thread owns m = 4t..4t+3

    const float* base = d + ((size_t)b * L + (size_t)lch * ROWS) * M + t * 4;
    float4 acc = make_float4(0.f, 0.f, 0.f, 0.f);
#pragma unroll 4
    for (int l = 0; l < ROWS; ++l) {
        float4 v = *reinterpret_cast<const float4*>(base + (size_t)l * M);
        acc.x += v.x; acc.y += v.y; acc.z += v.z; acc.w += v.w;
    }
    *reinterpret_cast<float4*>(partial + ((size_t)b * LCH + lch) * M + t * 4) = acc;
}

__global__ __launch_bounds__(256) void scale_and_idx(
    const float* __restrict__ partial, int* __restrict__ new_idx) {
    const int b = blockIdx.x;
    const int t = threadIdx.x;             // 256 threads, one float4 of m each
    const int m0 = t * 4;

    double c0 = 0.0, c1 = 0.0, c2 = 0.0, c3 = 0.0;
    for (int lch = 0; lch < LCH; ++lch) {
        float4 v = *reinterpret_cast<const float4*>(
            partial + ((size_t)b * LCH + lch) * M + m0);
        c0 += v.x; c1 += v.y; c2 += v.z; c3 += v.w;
    }
    double s0 = c0 + c1 + c2 + c3;
    double s1 = c0 * (double)m0 + c1 * (double)(m0 + 1) +
                c2 * (double)(m0 + 2) + c3 * (double)(m0 + 3);

    // wave (64-lane) butterfly reduce
#pragma unroll
    for (int off = 32; off > 0; off >>= 1) {
        s0 += __shfl_down(s0, off);
        s1 += __shfl_down(s1, off);
    }
    __shared__ double ls0[4], ls1[4];
    const int wave = t >> 6, lane = t & 63;
    if (lane == 0) { ls0[wave] = s0; ls1[wave] = s1; }
    __syncthreads();
    __shared__ float sscale;
    if (t == 0) {
        double S0 = ls0[0] + ls0[1] + ls0[2] + ls0[3];
        double S1 = ls1[0] + ls1[1] + ls1[2] + ls1[3];
        double mean = S1 / S0;                    // weighted mean distance
        sscale = (float)(mean / (0.5 * (double)M));
    }
    __syncthreads();
    const float sc = sscale;

    // mirror JAX: idx = clip(int32(f32(scale) * f32(m)), 0, M-1)
    int4 o;
    o.x = min(max((int)(sc * (float)(m0 + 0)), 0), M - 1);
    o.y = min(max((int)(sc * (float)(m0 + 1)), 0), M - 1);
    o.z = min(max((int)(sc * (float)(m0 + 2)), 0), M - 1);
    o.w = min(max((int)(sc * (float)(m0 + 3)), 0), M - 1);
    *reinterpret_cast<int4*>(new_idx + (size_t)b * M + m0) = o;
}

__global__ __launch_bounds__(256) void gather_rows(
    const float* __restrict__ d, const int* __restrict__ new_idx,
    float* __restrict__ out) {
    const int blk = blockIdx.x;            // b * L + l
    const int b   = blk >> 11;             // L = 2048
    const int t   = threadIdx.x;

    const float* row = d + (size_t)blk * M;
    const int4 idx = *reinterpret_cast<const int4*>(new_idx + (size_t)b * M + t * 4);
    float4 v;
    v.x = row[idx.x];
    v.y = row[idx.y];
    v.z = row[idx.z];
    v.w = row[idx.w];
    *reinterpret_cast<float4*>(out + (size_t)blk * M + t * 4) = v;
}

extern "C" void kernel_launch(void* const* d_in, const int* in_sizes, int n_in,
                              void* d_out, int out_size, void* d_ws, size_t ws_size,
                              hipStream_t stream) {
    const float* d = (const float*)d_in[0];
    float* out = (float*)d_out;
    const int n = in_sizes[0];
    const int B = n / (L * M);             // 16 for the bench shape

    float* partial = (float*)d_ws;                         // B*LCH*M f32 = 4 MiB
    int* new_idx   = (int*)((char*)d_ws + (size_t)B * LCH * M * sizeof(float));

    colsum_partial<<<B * LCH, 256, 0, stream>>>(d, partial);
    scale_and_idx<<<B, 256, 0, stream>>>(partial, new_idx);
    gather_rows<<<B * L, 256, 0, stream>>>(d, new_idx, out);
}

// Round 3
// 248.100 us; speedup vs baseline: 1.0512x; 1.0512x over previous
//
#include <hip/hip_runtime.h>

// DistanceNorm: (B, L, M) f32, B=16, L=2048, M=1024.
//  Kernel A: per-(b, L-chunk) reduce 32 rows -> f32 column sums -> f64 (s0, s1)
//            scalar pair per chunk; ws holds B*64*2 doubles = 16 KB.
//  Kernel C: every block butterfly-reduces the 64 chunk pairs (deterministic,
//            identical in all blocks) -> scale -> idx in registers -> gather
//            8 rows -> nontemporal float4 stores.
// Memory-bound: ~270 MB HBM min (read d once for reduce, re-read likely
// L3-resident, write out once).

typedef float f32x4 __attribute__((ext_vector_type(4)));  // native vector for
                                                          // nontemporal builtin

constexpr int L    = 2048;
constexpr int M    = 1024;
constexpr int LCH  = 64;           // chunks per batch in kernel A
constexpr int ROWS = L / LCH;      // 32 rows per chunk
constexpr int RPB  = 8;            // rows per gather block
constexpr int GPB  = L / RPB;      // 256 gather blocks per batch

__global__ __launch_bounds__(256) void colsum_reduce(
    const float* __restrict__ d, double* __restrict__ sums) {
    const int blk = blockIdx.x;            // b * LCH + lch
    const int b   = blk / LCH;
    const int lch = blk % LCH;
    const int t   = threadIdx.x;
    const int m0  = t * 4;

    const float* base = d + ((size_t)b * L + (size_t)lch * ROWS) * M + m0;
    float a0 = 0.f, a1 = 0.f, a2 = 0.f, a3 = 0.f;
#pragma unroll 8
    for (int l = 0; l < ROWS; ++l) {
        f32x4 v = *reinterpret_cast<const f32x4*>(base + (size_t)l * M);
        a0 += v.x; a1 += v.y; a2 += v.z; a3 += v.w;
    }
    double s0 = (double)a0 + (double)a1 + (double)a2 + (double)a3;
    double s1 = (double)a0 * (double)(m0 + 0) + (double)a1 * (double)(m0 + 1) +
                (double)a2 * (double)(m0 + 2) + (double)a3 * (double)(m0 + 3);

#pragma unroll
    for (int off = 32; off > 0; off >>= 1) {
        s0 += __shfl_down(s0, off);
        s1 += __shfl_down(s1, off);
    }
    __shared__ double ls0[4], ls1[4];
    const int wave = t >> 6, lane = t & 63;
    if (lane == 0) { ls0[wave] = s0; ls1[wave] = s1; }
    __syncthreads();
    if (t == 0) {
        double S0 = ls0[0] + ls0[1] + ls0[2] + ls0[3];
        double S1 = ls1[0] + ls1[1] + ls1[2] + ls1[3];
        sums[2 * (size_t)blk + 0] = S0;
        sums[2 * (size_t)blk + 1] = S1;
    }
}

__global__ __launch_bounds__(256) void gather_rows(
    const float* __restrict__ d, const double* __restrict__ sums,
    float* __restrict__ out) {
    const int blk = blockIdx.x;            // b * GPB + g
    const int b   = blk / GPB;
    const int l0  = (blk % GPB) * RPB;
    const int t   = threadIdx.x;

    // deterministic per-block scale: identical butterfly in every block
    __shared__ float sscale;
    if (t < 64) {
        double s0 = sums[(size_t)b * (2 * LCH) + 2 * t + 0];
        double s1 = sums[(size_t)b * (2 * LCH) + 2 * t + 1];
#pragma unroll
        for (int off = 32; off > 0; off >>= 1) {
            s0 += __shfl_down(s0, off);
            s1 += __shfl_down(s1, off);
        }
        if (t == 0) sscale = (float)((s1 / s0) / (0.5 * (double)M));
    }
    __syncthreads();
    const float sc = sscale;

    // mirror JAX: idx = clip(int32(f32(scale) * f32(m)), 0, M-1)
    const int m0 = t * 4;
    const int i0 = min(max((int)(sc * (float)(m0 + 0)), 0), M - 1);
    const int i1 = min(max((int)(sc * (float)(m0 + 1)), 0), M - 1);
    const int i2 = min(max((int)(sc * (float)(m0 + 2)), 0), M - 1);
    const int i3 = min(max((int)(sc * (float)(m0 + 3)), 0), M - 1);

    const float* rowbase = d   + ((size_t)b * L + l0) * M;
    float*       outbase = out + ((size_t)b * L + l0) * M;
#pragma unroll
    for (int r = 0; r < RPB; ++r) {
        const float* row = rowbase + (size_t)r * M;
        f32x4 v;
        v.x = row[i0];
        v.y = row[i1];
        v.z = row[i2];
        v.w = row[i3];
        __builtin_nontemporal_store(v,
            reinterpret_cast<f32x4*>(outbase + (size_t)r * M + m0));
    }
}

extern "C" void kernel_launch(void* const* d_in, const int* in_sizes, int n_in,
                              void* d_out, int out_size, void* d_ws, size_t ws_size,
                              hipStream_t stream) {
    const float* d = (const float*)d_in[0];
    float* out = (float*)d_out;
    const int n = in_sizes[0];
    const int B = n / (L * M);             // 16 for the bench shape

    double* sums = (double*)d_ws;          // B * LCH * 2 doubles = 16 KB

    colsum_reduce<<<B * LCH, 256, 0, stream>>>(d, sums);
    gather_rows<<<B * GPB, 256, 0, stream>>>(d, sums, out);
}